// Round 1
// baseline (278.833 us; speedup 1.0000x reference)
//
#include <hip/hip_runtime.h>

// Problem: B=32, F_IN=64, F_OUT=64, D=512, K=64
// out[(b,o),d] = sum_{k,e} T[(b,o),(k,e)] * W[k,e,d],
// T[(b,o),(k,e)] = sum_i coeff[o,i,k] * x[b,i,e]
// GEMM shape: M=2048, N=512, Kdim=32768 (bf16 MFMA, fp32 accum)

#define KK 32768   // K*D contraction length
#define M_ 2048    // B*F_OUT

typedef __attribute__((ext_vector_type(8))) short bf16x8;
typedef __attribute__((ext_vector_type(4))) float f32x4;

__device__ __forceinline__ unsigned short f2bf(float f) {
  unsigned int u = __float_as_uint(f);
  return (unsigned short)((u + 0x7FFFu + ((u >> 16) & 1u)) >> 16);  // RNE
}

__device__ __forceinline__ void gld16(void* lds, const void* g) {
  // async global->LDS, 16B per lane; LDS dest must be wave-uniform base + lane*16
  __builtin_amdgcn_global_load_lds((const __attribute__((address_space(1))) void*)g,
                                   (__attribute__((address_space(3))) void*)lds,
                                   16, 0, 0);
}

// ---- convert W fp32 [64][512(e)][512(d)] -> WbT bf16 [512(d)][64*512 (k,e)] (transpose e<->d)
__global__ __launch_bounds__(256) void convW(const float* __restrict__ W,
                                             unsigned short* __restrict__ WbT) {
  __shared__ float tile[32][33];
  int blk = blockIdx.x;                 // 64 k * 16 et * 16 dt
  int k = blk >> 8;
  int et = (blk >> 4) & 15, dt = blk & 15;
  int t = threadIdx.x;
  int tr = t >> 5;                      // 0..7
  int tc = t & 31;                      // 0..31
  const float* src = W + ((size_t)k * 512 + (size_t)et * 32) * 512 + dt * 32;
#pragma unroll
  for (int r = 0; r < 4; r++) {
    int e = tr + r * 8;
    tile[e][tc] = src[(size_t)e * 512 + tc];   // coalesced read over d
  }
  __syncthreads();
#pragma unroll
  for (int r = 0; r < 4; r++) {
    int dl = tr + r * 8;                // local d row
    WbT[(size_t)(dt * 32 + dl) * KK + k * 512 + et * 32 + tc] = f2bf(tile[tc][dl]);
  }
}

// ---- convert x fp32 [32][64(i)][512(e)] -> xT bf16 [32][512(e)][64(i)]
__global__ __launch_bounds__(256) void convX(const float* __restrict__ x,
                                             unsigned short* __restrict__ xT) {
  int tid = blockIdx.x * 256 + threadIdx.x;   // 1,048,576
  int b = tid >> 15;
  int r = tid & 32767;
  int e = r >> 6, i = r & 63;
  xT[tid] = f2bf(x[((size_t)(b * 64 + i)) * 512 + e]);
}

// ---- convert coeff fp32 [64(o)][64(i)][64(k)] -> cb bf16 [64(k)][64(o)][64(i)]
__global__ __launch_bounds__(256) void convC(const float* __restrict__ c,
                                             unsigned short* __restrict__ cb) {
  int tid = blockIdx.x * 256 + threadIdx.x;   // 262,144
  int k = tid >> 12, r = tid & 4095;          // r = o*64+i
  cb[tid] = f2bf(c[(size_t)r * 64 + k]);
}

// ---- T kernel: Tb[(b*64+o)][(kglob*512+e)] = sum_i cb[kglob][o][i] * xT[b][e][i]
// block: (b, kg of 2 words, e-half of 256). 4 waves, each owns 16 o's.
__global__ __launch_bounds__(256) void tkern(const unsigned short* __restrict__ xT,
                                             const unsigned short* __restrict__ cb,
                                             unsigned short* __restrict__ Tb) {
  // xe: [256 e][88 i] padded pitch (176 B) -> ~2-way LDS conflicts on B-frag reads
  __shared__ unsigned short xe[256 * 88];     // 45056 B
  __shared__ unsigned short ck[2 * 64 * 64];  // 16384 B
  int bx = blockIdx.x;                        // 32 b * 32 kg * 2 eh = 2048
  int b = bx >> 6, kg = (bx >> 1) & 31, eh = bx & 1;
  int t = threadIdx.x;
  {
    const bf16x8* src = (const bf16x8*)(xT + (size_t)b * 32768 + (size_t)eh * 16384);
    for (int c = t; c < 2048; c += 256) {     // 256 rows * 8 chunks
      int e = c >> 3, ic = c & 7;
      *(bf16x8*)(xe + e * 88 + ic * 8) = src[c];
    }
    const bf16x8* csrc = (const bf16x8*)(cb + (size_t)kg * 8192);
    bf16x8* cdst = (bf16x8*)ck;
    for (int c = t; c < 1024; c += 256) cdst[c] = csrc[c];
  }
  __syncthreads();
  int wid = t >> 6, lane = t & 63, q = lane >> 4, l16 = lane & 15;
  int otile = wid * 16;
#pragma unroll
  for (int k = 0; k < 2; k++) {
    const unsigned short* ckk = ck + k * 4096;
    // A-frag: A[m=o=l16][kk=i=q*8+j]
    bf16x8 a0 = *(const bf16x8*)(ckk + (otile + l16) * 64 + q * 8);
    bf16x8 a1 = *(const bf16x8*)(ckk + (otile + l16) * 64 + q * 8 + 32);
    int kglob = kg * 2 + k;
    size_t colbase = (size_t)kglob * 512 + (size_t)eh * 256;
    size_t rowbase = (size_t)b * 64;
    for (int et = 0; et < 16; et++) {
      int e = et * 16 + l16;
      // B-frag: B[kk=i=q*8+j][n=e=l16]
      bf16x8 b0 = *(const bf16x8*)(xe + e * 88 + q * 8);
      bf16x8 b1 = *(const bf16x8*)(xe + e * 88 + q * 8 + 32);
      f32x4 acc = {0.f, 0.f, 0.f, 0.f};
      acc = __builtin_amdgcn_mfma_f32_16x16x32_bf16(a0, b0, acc, 0, 0, 0);
      acc = __builtin_amdgcn_mfma_f32_16x16x32_bf16(a1, b1, acc, 0, 0, 0);
      // C/D: row(o) = q*4 + r2, col(e) = l16
#pragma unroll
      for (int r2 = 0; r2 < 4; r2++) {
        int o = otile + q * 4 + r2;
        Tb[(rowbase + o) * (size_t)KK + colbase + et * 16 + l16] = f2bf(acc[r2]);
      }
    }
  }
}

// ---- big GEMM: out[M=2048][N=512] += Tb[M][KK] * WbT[N][KK]^T ; split-K=8, atomic epilogue
__global__ __launch_bounds__(256) void gemm_kern(const unsigned short* __restrict__ A,
                                                 const unsigned short* __restrict__ Bt,
                                                 float* __restrict__ out) {
  __shared__ unsigned short As[128 * 32];   // 8 KB, row pitch 64 B
  __shared__ unsigned short Bs[128 * 32];   // 8 KB
  int bx = blockIdx.x;                      // 8 ks * 4 nt * 16 mt = 512
  int ks = bx & 7, nt = (bx >> 3) & 3, mt = bx >> 5;
  int m0 = mt * 128, n0 = nt * 128, k0 = ks * 4096;
  int t = threadIdx.x;
  int wid = t >> 6, lane = t & 63, q = lane >> 4, l16 = lane & 15;
  int wm = (wid & 1) * 64, wn = (wid >> 1) * 64;
  f32x4 acc[4][4] = {};
  int r1 = t >> 2;                          // staging row 0..63
  int o1 = (t & 3) * 16;                    // byte offset within 64B row segment
  const char* gabase = (const char*)(A + (size_t)m0 * KK + k0);
  const char* gbbase = (const char*)(Bt + (size_t)n0 * KK + k0);
#pragma unroll 1
  for (int kc = 0; kc < 4096; kc += 32) {
    const char* ga = gabase + (size_t)kc * 2;
    const char* gb = gbbase + (size_t)kc * 2;
    // stage A,B tiles [128 rows][32 cols] via direct-to-LDS 16B loads
    gld16((char*)As + t * 16, ga + (size_t)r1 * 65536 + o1);
    gld16((char*)As + (t + 256) * 16, ga + (size_t)(r1 + 64) * 65536 + o1);
    gld16((char*)Bs + t * 16, gb + (size_t)r1 * 65536 + o1);
    gld16((char*)Bs + (t + 256) * 16, gb + (size_t)(r1 + 64) * 65536 + o1);
    __syncthreads();
    bf16x8 af[4], bfr[4];
#pragma unroll
    for (int fr = 0; fr < 4; fr++)
      af[fr] = *(const bf16x8*)(As + (wm + fr * 16 + l16) * 32 + q * 8);
#pragma unroll
    for (int fc = 0; fc < 4; fc++)
      bfr[fc] = *(const bf16x8*)(Bs + (wn + fc * 16 + l16) * 32 + q * 8);
#pragma unroll
    for (int fr = 0; fr < 4; fr++)
#pragma unroll
      for (int fc = 0; fc < 4; fc++)
        acc[fr][fc] = __builtin_amdgcn_mfma_f32_16x16x32_bf16(af[fr], bfr[fc], acc[fr][fc], 0, 0, 0);
    __syncthreads();
  }
#pragma unroll
  for (int fr = 0; fr < 4; fr++)
#pragma unroll
    for (int fc = 0; fc < 4; fc++)
#pragma unroll
      for (int r = 0; r < 4; r++)
        atomicAdd(&out[(size_t)(m0 + wm + fr * 16 + q * 4 + r) * 512 + n0 + wn + fc * 16 + l16],
                  acc[fr][fc][r]);
}

// ---- fp32 fallback (only if ws too small): block = (b, k), correct but slow
__global__ __launch_bounds__(256) void fallback_kern(const float* __restrict__ x,
                                                     const float* __restrict__ W,
                                                     const float* __restrict__ coeff,
                                                     float* __restrict__ out) {
  __shared__ float ev[64][129];
  int b = blockIdx.x >> 6, k = blockIdx.x & 63;
  int t = threadIdx.x, dl = t & 127, half = t >> 7;
  const float* xb = x + (size_t)b * 64 * 512;
  const float* Wk = W + (size_t)k * 512 * 512;
  for (int dc = 0; dc < 4; dc++) {
    int d = dc * 128 + dl;
    for (int i = half * 32; i < half * 32 + 32; i++) {
      float acc = 0.f;
      const float* xr = xb + (size_t)i * 512;
#pragma unroll 4
      for (int e = 0; e < 512; e++) acc += xr[e] * Wk[(size_t)e * 512 + d];
      ev[i][dl] = acc;
    }
    __syncthreads();
    for (int o = half * 32; o < half * 32 + 32; o++) {
      float s = 0.f;
#pragma unroll 8
      for (int i = 0; i < 64; i++) s += coeff[((size_t)o * 64 + i) * 64 + k] * ev[i][dl];
      atomicAdd(&out[((size_t)(b * 64 + o)) * 512 + d], s);
    }
    __syncthreads();
  }
}

extern "C" void kernel_launch(void* const* d_in, const int* in_sizes, int n_in,
                              void* d_out, int out_size, void* d_ws, size_t ws_size,
                              hipStream_t stream) {
  const float* x = (const float*)d_in[0];
  const float* W = (const float*)d_in[1];
  const float* coeff = (const float*)d_in[2];
  float* out = (float*)d_out;
  const size_t OFF_XT = 33554432;            // WbT: 512*32768*2
  const size_t OFF_CB = OFF_XT + 2097152;    // xT : 32*512*64*2
  const size_t OFF_TB = OFF_CB + 524288;     // cb : 64*64*64*2
  const size_t NEED = OFF_TB + 134217728;    // Tb : 2048*32768*2  => 170,393,600 B

  hipMemsetAsync(d_out, 0, (size_t)out_size * sizeof(float), stream);
  if (ws_size >= NEED) {
    unsigned short* WbT = (unsigned short*)d_ws;
    unsigned short* xT  = (unsigned short*)((char*)d_ws + OFF_XT);
    unsigned short* cb  = (unsigned short*)((char*)d_ws + OFF_CB);
    unsigned short* Tb  = (unsigned short*)((char*)d_ws + OFF_TB);
    convW<<<16384, 256, 0, stream>>>(W, WbT);
    convX<<<4096, 256, 0, stream>>>(x, xT);
    convC<<<1024, 256, 0, stream>>>(coeff, cb);
    tkern<<<2048, 256, 0, stream>>>(xT, cb, Tb);
    gemm_kern<<<512, 256, 0, stream>>>(Tb, WbT, out);
  } else {
    fallback_kern<<<2048, 256, 0, stream>>>(x, W, coeff, out);
  }
}

// Round 2
// 251.925 us; speedup vs baseline: 1.1068x; 1.1068x over previous
//
#include <hip/hip_runtime.h>

// Problem: B=32, F_IN=64, F_OUT=64, D=512, K=64
// out[(b,o),d] = sum_{k,e} T[(b,o),(k,e)] * W[k,e,d],
// T[(b,o),(k,e)] = sum_i coeff[o,i,k] * x[b,i,e]
// GEMM shape: M=2048, N=512, Kdim=32768 (bf16 MFMA, fp32 accum)

#define KK 32768   // K*D contraction length

typedef __attribute__((ext_vector_type(8))) short bf16x8;
typedef __attribute__((ext_vector_type(4))) float f32x4;

__device__ __forceinline__ unsigned short f2bf(float f) {
  unsigned int u = __float_as_uint(f);
  return (unsigned short)((u + 0x7FFFu + ((u >> 16) & 1u)) >> 16);  // RNE
}

__device__ __forceinline__ void gld16(void* lds, const void* g) {
  __builtin_amdgcn_global_load_lds((const __attribute__((address_space(1))) void*)g,
                                   (__attribute__((address_space(3))) void*)lds,
                                   16, 0, 0);
}

// ---- convert W fp32 [64][512(e)][512(d)] -> WbT bf16 [512(d)][64*512 (k,e)]
// 64x64 LDS fp32 transpose tile; writes are ushort4 (8B) in 128B coalesced runs.
__global__ __launch_bounds__(256) void convW(const float* __restrict__ W,
                                             unsigned short* __restrict__ WbT) {
  __shared__ float tile[64][65];
  int bx = blockIdx.x;                 // 64 k * 8 et * 8 dt = 4096
  int k = bx >> 6, et = (bx >> 3) & 7, dt = bx & 7;
  int t = threadIdx.x;
  const float* src = W + ((size_t)k * 512 + (size_t)et * 64) * 512 + dt * 64;
  int rr = t >> 6, cc = t & 63;
#pragma unroll
  for (int p = 0; p < 16; p++) {
    int e = p * 4 + rr;
    tile[e][cc] = src[(size_t)e * 512 + cc];   // 256B coalesced per row
  }
  __syncthreads();
  int dl = t >> 4, eg = t & 15;
#pragma unroll
  for (int p = 0; p < 4; p++) {
    int d = p * 16 + dl;
    ushort4 v;
    v.x = f2bf(tile[eg * 4 + 0][d]);
    v.y = f2bf(tile[eg * 4 + 1][d]);
    v.z = f2bf(tile[eg * 4 + 2][d]);
    v.w = f2bf(tile[eg * 4 + 3][d]);
    *(ushort4*)(WbT + (size_t)(dt * 64 + d) * KK + k * 512 + et * 64 + eg * 4) = v;
  }
}

// ---- convert x fp32 [32][64(i)][512(e)] -> xT bf16 [32][512(e)][64(i)]
__global__ __launch_bounds__(256) void convX(const float* __restrict__ x,
                                             unsigned short* __restrict__ xT) {
  int tid = blockIdx.x * 256 + threadIdx.x;   // 1,048,576
  int b = tid >> 15;
  int r = tid & 32767;
  int e = r >> 6, i = r & 63;
  xT[tid] = f2bf(x[((size_t)(b * 64 + i)) * 512 + e]);
}

// ---- convert coeff fp32 [64(o)][64(i)][64(k)] -> cb bf16 [64(k)][64(o)][64(i)]
__global__ __launch_bounds__(256) void convC(const float* __restrict__ c,
                                             unsigned short* __restrict__ cb) {
  int tid = blockIdx.x * 256 + threadIdx.x;   // 262,144
  int k = tid >> 12, r = tid & 4095;
  cb[tid] = f2bf(c[(size_t)r * 64 + k]);
}

// ---- T kernel: Tb[(b*64+o)][(k*512+e)] = sum_i cb[k][o][i] * xT[b][e][i]
// block = (b, k, e-quarter of 128). Output staged in LDS, stored as bf16x8 in 256B runs.
__global__ __launch_bounds__(256) void tkern(const unsigned short* __restrict__ xT,
                                             const unsigned short* __restrict__ cb,
                                             unsigned short* __restrict__ Tb) {
  __shared__ unsigned short xe[128 * 88];   // 22528 B (pitch 176B: conflict-free frag reads)
  __shared__ unsigned short ck[64 * 64];    // 8192 B
  __shared__ unsigned short ot[64 * 136];   // 17408 B (pitch 272B, 16B-aligned)
  int bx = blockIdx.x;                      // 32 b * 64 k * 4 eq = 8192
  int b = bx >> 8, k = (bx >> 2) & 63, eq = bx & 3;
  int t = threadIdx.x;
  {
    const bf16x8* src = (const bf16x8*)(xT + (size_t)b * 32768 + (size_t)eq * 128 * 64);
#pragma unroll
    for (int j = 0; j < 4; j++) {
      int idx = j * 256 + t, e = idx >> 3, c = idx & 7;
      *(bf16x8*)(xe + e * 88 + c * 8) = src[idx];
    }
    const bf16x8* cs = (const bf16x8*)(cb + (size_t)k * 4096);
#pragma unroll
    for (int j = 0; j < 2; j++) *(bf16x8*)(ck + (j * 256 + t) * 8) = cs[j * 256 + t];
  }
  __syncthreads();
  int wid = t >> 6, lane = t & 63, q = lane >> 4, l16 = lane & 15;
  int o0 = wid * 16;
  // A-frag: A[m=o=l16][kk=i=q*8+j]
  bf16x8 a0 = *(const bf16x8*)(ck + (o0 + l16) * 64 + q * 8);
  bf16x8 a1 = *(const bf16x8*)(ck + (o0 + l16) * 64 + q * 8 + 32);
#pragma unroll
  for (int et = 0; et < 8; et++) {
    int e = et * 16 + l16;
    bf16x8 b0 = *(const bf16x8*)(xe + e * 88 + q * 8);
    bf16x8 b1 = *(const bf16x8*)(xe + e * 88 + q * 8 + 32);
    f32x4 acc = {0.f, 0.f, 0.f, 0.f};
    acc = __builtin_amdgcn_mfma_f32_16x16x32_bf16(a0, b0, acc, 0, 0, 0);
    acc = __builtin_amdgcn_mfma_f32_16x16x32_bf16(a1, b1, acc, 0, 0, 0);
#pragma unroll
    for (int r2 = 0; r2 < 4; r2++)
      ot[(o0 + q * 4 + r2) * 136 + et * 16 + l16] = f2bf(acc[r2]);
  }
  __syncthreads();
  size_t base = ((size_t)(b * 64)) * KK + k * 512 + eq * 128;
#pragma unroll
  for (int j = 0; j < 4; j++) {
    int idx = j * 256 + t, o = idx >> 4, c = idx & 15;
    *(bf16x8*)(Tb + base + (size_t)o * KK + c * 8) = *(const bf16x8*)(ot + o * 136 + c * 8);
  }
}

// ---- big GEMM: out[2048][512] += Tb[M][KK] * WbT[N][KK]^T
// split-K=16 (1024 blocks, 4/CU), BK=64, XOR-swizzled LDS chunk slots (conflict-free).
__global__ __launch_bounds__(256, 4) void gemm_kern(const unsigned short* __restrict__ A,
                                                    const unsigned short* __restrict__ Bt,
                                                    float* __restrict__ out) {
  __shared__ unsigned short As[128 * 64];   // 16 KB, row pitch 128 B (8 chunks of 16 B)
  __shared__ unsigned short Bs[128 * 64];   // 16 KB
  int bx = blockIdx.x;                      // 16 ks * 4 nt * 16 mt = 1024
  int ks = bx & 15, nt = (bx >> 4) & 3, mt = bx >> 6;
  int m0 = mt * 128, n0 = nt * 128, k0 = ks * 2048;
  int t = threadIdx.x;
  int wid = t >> 6, lane = t & 63, q = lane >> 4, l16 = lane & 15;
  int wm = (wid & 1) * 64, wn = (wid >> 1) * 64;
  f32x4 acc[4][4] = {};
  // staging: lane t handles (row = j*32 + t>>3, slot = t&7); loads global chunk slot^(row&7)
  int srow = t >> 3;
  int cg = (t & 7) ^ (srow & 7);            // row&7 == (t>>3)&7 for all j
  const char* gabase = (const char*)(A + (size_t)m0 * KK + k0) + (size_t)srow * 65536 + cg * 16;
  const char* gbbase = (const char*)(Bt + (size_t)n0 * KK + k0) + (size_t)srow * 65536 + cg * 16;
  // frag-read swizzled slot (row&7 == l16&7 since wm,fr*16 are mult of 8)
  int sw0 = q ^ (l16 & 7);                  // ks2=0 slot
  int sw1 = (4 | q) ^ (l16 & 7);            // ks2=1 slot
#pragma unroll 1
  for (int kc = 0; kc < 2048; kc += 64) {
    const char* ga = gabase + (size_t)kc * 2;
    const char* gb = gbbase + (size_t)kc * 2;
#pragma unroll
    for (int j = 0; j < 4; j++) {
      gld16((char*)As + (j * 256 + t) * 16, ga + (size_t)j * 32 * 65536);
      gld16((char*)Bs + (j * 256 + t) * 16, gb + (size_t)j * 32 * 65536);
    }
    __syncthreads();
#pragma unroll
    for (int ks2 = 0; ks2 < 2; ks2++) {
      int slot = ks2 ? sw1 : sw0;
      bf16x8 af[4], bfr[4];
#pragma unroll
      for (int fr = 0; fr < 4; fr++)
        af[fr] = *(const bf16x8*)(As + (wm + fr * 16 + l16) * 64 + slot * 8);
#pragma unroll
      for (int fc = 0; fc < 4; fc++)
        bfr[fc] = *(const bf16x8*)(Bs + (wn + fc * 16 + l16) * 64 + slot * 8);
#pragma unroll
      for (int fr = 0; fr < 4; fr++)
#pragma unroll
        for (int fc = 0; fc < 4; fc++)
          acc[fr][fc] = __builtin_amdgcn_mfma_f32_16x16x32_bf16(af[fr], bfr[fc], acc[fr][fc], 0, 0, 0);
    }
    __syncthreads();
  }
#pragma unroll
  for (int fr = 0; fr < 4; fr++)
#pragma unroll
    for (int fc = 0; fc < 4; fc++)
#pragma unroll
      for (int r = 0; r < 4; r++)
        atomicAdd(&out[(size_t)(m0 + wm + fr * 16 + q * 4 + r) * 512 + n0 + wn + fc * 16 + l16],
                  acc[fr][fc][r]);
}

// ---- fp32 fallback (only if ws too small)
__global__ __launch_bounds__(256) void fallback_kern(const float* __restrict__ x,
                                                     const float* __restrict__ W,
                                                     const float* __restrict__ coeff,
                                                     float* __restrict__ out) {
  __shared__ float ev[64][129];
  int b = blockIdx.x >> 6, k = blockIdx.x & 63;
  int t = threadIdx.x, dl = t & 127, half = t >> 7;
  const float* xb = x + (size_t)b * 64 * 512;
  const float* Wk = W + (size_t)k * 512 * 512;
  for (int dc = 0; dc < 4; dc++) {
    int d = dc * 128 + dl;
    for (int i = half * 32; i < half * 32 + 32; i++) {
      float acc = 0.f;
      const float* xr = xb + (size_t)i * 512;
#pragma unroll 4
      for (int e = 0; e < 512; e++) acc += xr[e] * Wk[(size_t)e * 512 + d];
      ev[i][dl] = acc;
    }
    __syncthreads();
    for (int o = half * 32; o < half * 32 + 32; o++) {
      float s = 0.f;
#pragma unroll 8
      for (int i = 0; i < 64; i++) s += coeff[((size_t)o * 64 + i) * 64 + k] * ev[i][dl];
      atomicAdd(&out[((size_t)(b * 64 + o)) * 512 + d], s);
    }
    __syncthreads();
  }
}

extern "C" void kernel_launch(void* const* d_in, const int* in_sizes, int n_in,
                              void* d_out, int out_size, void* d_ws, size_t ws_size,
                              hipStream_t stream) {
  const float* x = (const float*)d_in[0];
  const float* W = (const float*)d_in[1];
  const float* coeff = (const float*)d_in[2];
  float* out = (float*)d_out;
  const size_t OFF_XT = 33554432;            // WbT: 512*32768*2
  const size_t OFF_CB = OFF_XT + 2097152;    // xT : 32*512*64*2
  const size_t OFF_TB = OFF_CB + 524288;     // cb : 64*64*64*2
  const size_t NEED = OFF_TB + 134217728;    // Tb : 2048*32768*2

  hipMemsetAsync(d_out, 0, (size_t)out_size * sizeof(float), stream);
  if (ws_size >= NEED) {
    unsigned short* WbT = (unsigned short*)d_ws;
    unsigned short* xT  = (unsigned short*)((char*)d_ws + OFF_XT);
    unsigned short* cb  = (unsigned short*)((char*)d_ws + OFF_CB);
    unsigned short* Tb  = (unsigned short*)((char*)d_ws + OFF_TB);
    convW<<<4096, 256, 0, stream>>>(W, WbT);
    convX<<<4096, 256, 0, stream>>>(x, xT);
    convC<<<1024, 256, 0, stream>>>(coeff, cb);
    tkern<<<8192, 256, 0, stream>>>(xT, cb, Tb);
    gemm_kern<<<1024, 256, 0, stream>>>(Tb, WbT, out);
  } else {
    fallback_kern<<<2048, 256, 0, stream>>>(x, W, coeff, out);
  }
}